// Round 6
// baseline (614.156 us; speedup 1.0000x reference)
//
#include <hip/hip_runtime.h>

// Board: 4096 x 4096 int32 in {0,1,2}  (0=empty, 1=black, 2=white)
// Outputs BOOLEAN -> int32 (0/1), concatenated flat in d_out:
//   bamboo_b, bamboo_w, tiger_b, tiger_w, etri_b, etri_w  -> each (4095,4095)
//   eye_b, eye_w                                          -> each (4094,4094)
//
// R6 = R3 strip (8 output rows/block, rolling 3-row register window ->
//      board fetched 1.25x) + R5 phase-aligned 16B stores.
// Alignment: plane p base = p*N1 (N1%4==1); row offset i*4095 % 4 == (-i)&3
//   -> aligned column phase for plane p is (i-p)&3. Eye planes (base 6*N1,
//   6*N1%4==2, row stride 4094): phase = i odd ? 0 : 2.
// i0 = blockIdx.y*8 is a multiple of 8 => i&3 == r&3 and i parity == r parity,
// compile-time in the unrolled row loop -> the phase switch folds away.

#define BW 4096
#define W1 4095
#define W2 4094
#define N1 16769025   // 4095*4095, % 4 == 1
#define N2 16760836   // 4094*4094, % 4 == 0
#define ROWS 8

typedef int i4a __attribute__((vector_size(16), aligned(16)));

template<int PH>
__device__ __forceinline__ void store_row(
    int* __restrict__ out, const int i, const int u, const bool has2,
    const int (&cellm)[7], const int (&eyem)[6])
{
    const bool fullv = (u < 1023);
    const size_t orow = (size_t)i * W1 + (u << 2);

    #pragma unroll
    for (int p = 0; p < 6; ++p) {
        const int sp = (PH - p) & 3;           // compile-time
        int* dst = out + (size_t)p * N1 + orow;
        if (fullv) {
            i4a s;
            s[0] = (cellm[sp + 0] >> p) & 1;
            s[1] = (cellm[sp + 1] >> p) & 1;
            s[2] = (cellm[sp + 2] >> p) & 1;
            s[3] = (cellm[sp + 3] >> p) & 1;
            *(i4a*)(dst + sp) = s;             // 16B-aligned by construction
        } else {                               // u == 1023: cols 4092+sp .. 4094
            #pragma unroll
            for (int k = 0; k < 3 - sp; ++k)
                dst[sp + k] = (cellm[sp + k] >> p) & 1;
        }
        if (u == 0) {                          // head cols 0 .. sp-1
            #pragma unroll
            for (int k = 0; k < sp; ++k)
                dst[k] = (cellm[k] >> p) & 1;
        }
    }

    if (has2) {
        const int e = (PH & 1) ? 0 : 2;        // compile-time eye phase
        int* d0 = out + (size_t)6 * N1 + (size_t)i * W2 + (u << 2);
        int* d1 = d0 + N2;
        if (fullv) {
            i4a s0, s1;
            #pragma unroll
            for (int k = 0; k < 4; ++k) {
                s0[k] =  eyem[e + k]       & 1;
                s1[k] = (eyem[e + k] >> 1) & 1;
            }
            *(i4a*)(d0 + e) = s0;              // 16B-aligned by construction
            *(i4a*)(d1 + e) = s1;
        } else if (e == 0) {                   // u == 1023: cols 4092, 4093
            #pragma unroll
            for (int k = 0; k < 2; ++k) {
                d0[k] =  eyem[k]       & 1;
                d1[k] = (eyem[k] >> 1) & 1;
            }
        }
        if (u == 0) {                          // head cols 0 .. e-1
            #pragma unroll
            for (int k = 0; k < e; ++k) {
                d0[k] =  eyem[k]       & 1;
                d1[k] = (eyem[k] >> 1) & 1;
            }
        }
    }
}

__global__ __launch_bounds__(256)
void motif_kernel(const int* __restrict__ board, int* __restrict__ out) {
    const int u    = blockIdx.x * 256 + threadIdx.x;  // 0..1023
    const int i0   = blockIdx.y * ROWS;               // multiple of 8
    const int base = u << 2;
    const bool fullv = (u < 1023);

    int r0[8], r1[8], r2[8];

    auto load_row = [&](const int* p, int* w) {
        i4a v = *(const i4a*)p;                       // 16B aligned
        w[0] = v[0]; w[1] = v[1]; w[2] = v[2]; w[3] = v[3];
        if (fullv) {
            i4a x = *(const i4a*)(p + 4);
            w[4] = x[0]; w[5] = x[1]; w[6] = x[2]; w[7] = x[3];
        } else { w[4] = 0; w[5] = 0; w[6] = 0; w[7] = 0; }
    };

    load_row(board + (size_t)i0 * BW + base, r0);         // row i0
    load_row(board + (size_t)(i0 + 1) * BW + base, r1);   // row i0+1

    #pragma unroll
    for (int r = 0; r < ROWS; ++r) {
        const int i = i0 + r;
        if (i >= W1) break;                               // block-uniform
        const bool has2 = (i < W2);
        if (has2)
            load_row(board + (size_t)(i + 2) * BW + base, r2);

        // Packed motif bits for 2x2 cells at window positions 0..6:
        // bit0 bamboo_b, bit1 bamboo_w, bit2 tiger_b, bit3 tiger_w,
        // bit4 etri_b,   bit5 etri_w
        int cellm[7];
        #pragma unroll
        for (int p = 0; p < 7; ++p) {
            const int a = r0[p], b = r0[p + 1], c = r1[p], d = r1[p + 1];
            const int nb_d = (a == 1) + (d == 1), nb_a = (b == 1) + (c == 1);
            const int nw_d = (a == 2) + (d == 2), nw_a = (b == 2) + (c == 2);
            const int ne_d = (a == 0) + (d == 0), ne_a = (b == 0) + (c == 0);
            const int nb = nb_d + nb_a, nw = nw_d + nw_a, ne = ne_d + ne_a;
            const int bb  = ((nb_d == 2) & (ne_a == 2)) | ((nb_a == 2) & (ne_d == 2));
            const int bw_ = ((nw_d == 2) & (ne_a == 2)) | ((nw_a == 2) & (ne_d == 2));
            const int anyE = (ne >= 1);
            const int tb = (nb >= 2) & anyE;
            const int tw = (nw >= 2) & anyE;
            const int eb = (nb == 3) & (ne == 1);
            const int ew = (nw == 3) & (ne == 1);
            cellm[p] = bb | (bw_ << 1) | (tb << 2) | (tw << 3) | (eb << 4) | (ew << 5);
        }

        // Packed eye bits for positions 0..5: bit0 eye_b, bit1 eye_w
        int eyem[6];
        #pragma unroll
        for (int q = 0; q < 6; ++q) {
            const int ce = r1[q + 1], up = r0[q + 1], lf = r1[q],
                      dn = r2[q + 1], rt = r1[q + 2];
            const int eB = (ce == 0) & (up == 1) & (lf == 1) & (dn == 1) & (rt == 1);
            const int eW = (ce == 0) & (up == 2) & (lf == 2) & (dn == 2) & (rt == 2);
            eyem[q] = eB | (eW << 1);
        }

        // i0 % 8 == 0 -> (i & 3) == (r & 3): folds to one case per unrolled r
        switch (r & 3) {
            case 0: store_row<0>(out, i, u, has2, cellm, eyem); break;
            case 1: store_row<1>(out, i, u, has2, cellm, eyem); break;
            case 2: store_row<2>(out, i, u, has2, cellm, eyem); break;
            case 3: store_row<3>(out, i, u, has2, cellm, eyem); break;
        }

        #pragma unroll
        for (int q = 0; q < 8; ++q) { r0[q] = r1[q]; r1[q] = r2[q]; }
    }
}

extern "C" void kernel_launch(void* const* d_in, const int* in_sizes, int n_in,
                              void* d_out, int out_size, void* d_ws, size_t ws_size,
                              hipStream_t stream) {
    const int* board = (const int*)d_in[0];
    int* out = (int*)d_out;

    dim3 block(256, 1, 1);
    dim3 grid(4, (W1 + ROWS - 1) / ROWS, 1);   // 4 x 512 blocks, 8 rows each
    motif_kernel<<<grid, block, 0, stream>>>(board, out);
}

// Round 8
// 596.086 us; speedup vs baseline: 1.0303x; 1.0303x over previous
//
#include <hip/hip_runtime.h>

// Board: 4096 x 4096 int32 in {0,1,2}  (0=empty, 1=black, 2=white)
// Outputs BOOLEAN -> int32 (0/1), concatenated flat in d_out:
//   bamboo_b, bamboo_w, tiger_b, tiger_w, etri_b, etri_w  -> each (4095,4095)
//   eye_b, eye_w                                          -> each (4094,4094)
//
// R8 = R7 with the #pragma-in-else syntax error fixed.
// R5 phase-aligned 16B stores + 2 output rows per block sharing 4 board-row
// loads (fetch 201 -> 134 MB). i0 = 2*blockIdx.y so i0&3 in {0,2} ->
// compile-time store phases, small code per executed path.

#define BW 4096
#define W1 4095
#define W2 4094
#define N1 16769025   // 4095*4095, % 4 == 1
#define N2 16760836   // 4094*4094, % 4 == 0

typedef int i4a __attribute__((vector_size(16), aligned(16)));

template<int PH>
__device__ __forceinline__ void store_row(
    int* __restrict__ out, const int i, const int u, const bool has2,
    const int (&cellm)[7], const int (&eyem)[6])
{
    const bool fullv = (u < 1023);
    const size_t orow = (size_t)i * W1 + (u << 2);

    #pragma unroll
    for (int p = 0; p < 6; ++p) {
        const int sp = (PH - p) & 3;           // compile-time
        int* dst = out + (size_t)p * N1 + orow;
        if (fullv) {
            i4a s;
            s[0] = (cellm[sp + 0] >> p) & 1;
            s[1] = (cellm[sp + 1] >> p) & 1;
            s[2] = (cellm[sp + 2] >> p) & 1;
            s[3] = (cellm[sp + 3] >> p) & 1;
            *(i4a*)(dst + sp) = s;             // 16B-aligned by construction
        } else {                               // u == 1023: cols 4092+sp .. 4094
            #pragma unroll
            for (int k = 0; k < 3 - sp; ++k)
                dst[sp + k] = (cellm[sp + k] >> p) & 1;
        }
        if (u == 0) {                          // head cols 0 .. sp-1
            #pragma unroll
            for (int k = 0; k < sp; ++k)
                dst[k] = (cellm[k] >> p) & 1;
        }
    }

    if (has2) {
        const int e = (PH & 1) ? 0 : 2;        // compile-time eye phase
        int* d0 = out + (size_t)6 * N1 + (size_t)i * W2 + (u << 2);
        int* d1 = d0 + N2;
        if (fullv) {
            i4a s0, s1;
            #pragma unroll
            for (int k = 0; k < 4; ++k) {
                s0[k] =  eyem[e + k]       & 1;
                s1[k] = (eyem[e + k] >> 1) & 1;
            }
            *(i4a*)(d0 + e) = s0;              // 16B-aligned by construction
            *(i4a*)(d1 + e) = s1;
        } else if (e == 0) {                   // u == 1023: cols 4092, 4093
            #pragma unroll
            for (int k = 0; k < 2; ++k) {
                d0[k] =  eyem[k]       & 1;
                d1[k] = (eyem[k] >> 1) & 1;
            }
        }
        if (u == 0) {                          // head cols 0 .. e-1
            #pragma unroll
            for (int k = 0; k < e; ++k) {
                d0[k] =  eyem[k]       & 1;
                d1[k] = (eyem[k] >> 1) & 1;
            }
        }
    }
}

__device__ __forceinline__ void compute_masks(
    const int (&r0)[8], const int (&r1)[8], const int (&r2)[8],
    int (&cellm)[7], int (&eyem)[6])
{
    // Packed motif bits for 2x2 cells at window positions 0..6:
    // bit0 bamboo_b, bit1 bamboo_w, bit2 tiger_b, bit3 tiger_w,
    // bit4 etri_b,   bit5 etri_w
    #pragma unroll
    for (int p = 0; p < 7; ++p) {
        const int a = r0[p], b = r0[p + 1], c = r1[p], d = r1[p + 1];
        const int nb_d = (a == 1) + (d == 1), nb_a = (b == 1) + (c == 1);
        const int nw_d = (a == 2) + (d == 2), nw_a = (b == 2) + (c == 2);
        const int ne_d = (a == 0) + (d == 0), ne_a = (b == 0) + (c == 0);
        const int nb = nb_d + nb_a, nw = nw_d + nw_a, ne = ne_d + ne_a;
        const int bb  = ((nb_d == 2) & (ne_a == 2)) | ((nb_a == 2) & (ne_d == 2));
        const int bw_ = ((nw_d == 2) & (ne_a == 2)) | ((nw_a == 2) & (ne_d == 2));
        const int anyE = (ne >= 1);
        const int tb = (nb >= 2) & anyE;
        const int tw = (nw >= 2) & anyE;
        const int eb = (nb == 3) & (ne == 1);
        const int ew = (nw == 3) & (ne == 1);
        cellm[p] = bb | (bw_ << 1) | (tb << 2) | (tw << 3) | (eb << 4) | (ew << 5);
    }
    // Packed eye bits for positions 0..5: bit0 eye_b, bit1 eye_w
    #pragma unroll
    for (int q = 0; q < 6; ++q) {
        const int ce = r1[q + 1], up = r0[q + 1], lf = r1[q],
                  dn = r2[q + 1], rt = r1[q + 2];
        const int eB = (ce == 0) & (up == 1) & (lf == 1) & (dn == 1) & (rt == 1);
        const int eW = (ce == 0) & (up == 2) & (lf == 2) & (dn == 2) & (rt == 2);
        eyem[q] = eB | (eW << 1);
    }
}

template<int I0M4>   // i0 & 3: 0 or 2
__device__ __forceinline__ void strip_body(
    const int* __restrict__ board, int* __restrict__ out,
    const int u, const int i0)
{
    const int base = u << 2;
    const bool fullv = (u < 1023);
    const bool lastStrip = (i0 == W1 - 1);    // i0 == 4094: only row i0, no eyes

    int r0[8], r1[8], r2[8], r3[8];

    auto load_row = [&](int row, int* w) {
        const int* p = board + (size_t)row * BW + base;
        i4a v = *(const i4a*)p;               // 16B aligned
        w[0] = v[0]; w[1] = v[1]; w[2] = v[2]; w[3] = v[3];
        if (fullv) {
            i4a x = *(const i4a*)(p + 4);
            w[4] = x[0]; w[5] = x[1]; w[6] = x[2]; w[7] = x[3];
        } else { w[4] = 0; w[5] = 0; w[6] = 0; w[7] = 0; }
    };

    load_row(i0, r0);
    load_row(i0 + 1, r1);
    if (!lastStrip) {
        load_row(i0 + 2, r2);
        load_row(i0 + 3, r3);
    } else {
        for (int q = 0; q < 8; ++q) { r2[q] = 0; r3[q] = 0; }
    }

    int cellm[7], eyem[6];

    // output row i0  (eyes need row i0+2 -> only if !lastStrip)
    compute_masks(r0, r1, r2, cellm, eyem);
    store_row<I0M4>(out, i0, u, !lastStrip, cellm, eyem);

    // output row i0+1 (exists iff i0+1 < W1 <=> !lastStrip); eyes need i0+3:
    // i0+1 < W2 <=> i0 < 4093, true for all even i0 <= 4092
    if (!lastStrip) {
        compute_masks(r1, r2, r3, cellm, eyem);
        store_row<(I0M4 + 1) & 3>(out, i0 + 1, u, true, cellm, eyem);
    }
}

__global__ __launch_bounds__(256)
void motif_kernel(const int* __restrict__ board, int* __restrict__ out) {
    const int u  = blockIdx.x * 256 + threadIdx.x;  // 0..1023
    const int i0 = blockIdx.y << 1;                 // 0,2,...,4094

    if ((i0 & 2) == 0) strip_body<0>(board, out, u, i0);
    else               strip_body<2>(board, out, u, i0);
}

extern "C" void kernel_launch(void* const* d_in, const int* in_sizes, int n_in,
                              void* d_out, int out_size, void* d_ws, size_t ws_size,
                              hipStream_t stream) {
    const int* board = (const int*)d_in[0];
    int* out = (int*)d_out;

    dim3 block(256, 1, 1);
    dim3 grid(4, 2048, 1);   // 2 output rows per block (last block: 1 row)
    motif_kernel<<<grid, block, 0, stream>>>(board, out);
}